// Round 2
// baseline (10778.511 us; speedup 1.0000x reference)
//
#include <hip/hip_runtime.h>
#include <stdint.h>

#define TB 8192
#define NBATCH 2
#define RES_C 512
#define SKIP_C 256
#define MEL_C 80
#define NLAYERS 30

typedef short v8s __attribute__((ext_vector_type(8)));
typedef float v4f __attribute__((ext_vector_type(4)));
typedef unsigned short v4u16 __attribute__((ext_vector_type(4)));
typedef unsigned short v8u16 __attribute__((ext_vector_type(8)));

__device__ __forceinline__ unsigned short bf16rne(float f) {
    unsigned u = __float_as_uint(f);
    return (unsigned short)((u + 0x7fffu + ((u >> 16) & 1u)) >> 16);
}
__device__ __forceinline__ float bf2f(unsigned short h) {
    return __uint_as_float((unsigned)h << 16);
}
__device__ __forceinline__ float fsigmoid(float x) { return 1.0f / (1.0f + __expf(-x)); }
__device__ __forceinline__ float ftanh_(float x) { return 2.0f / (1.0f + __expf(-2.0f * x)) - 1.0f; }

// async 16B global->LDS (linear dest: wave-uniform base + lane*16)
__device__ __forceinline__ void gld16(const void* g, void* l) {
    __builtin_amdgcn_global_load_lds(
        (const __attribute__((address_space(1))) unsigned int*)g,
        (__attribute__((address_space(3))) unsigned int*)l, 16, 0, 0);
}

// ---------------- prep: pack weights to bf16 hi/lo ----------------
// Wd dst layout: [layer][tap][cout 1024][cin 512] (cin contiguous)
__global__ void k0_pack(const float* __restrict__ dil_w,
                        const float* __restrict__ res_w,
                        const float* __restrict__ skip_w,
                        unsigned short* __restrict__ WdH, unsigned short* __restrict__ WdL,
                        unsigned short* __restrict__ WrH, unsigned short* __restrict__ WrL,
                        unsigned short* __restrict__ WsH, unsigned short* __restrict__ WsL,
                        int split)
{
    const int NWd3 = NLAYERS * 1024 * 512;   // triples
    const int NWr = NLAYERS * 512 * 512;
    const int NWs = NLAYERS * 256 * 512;
    const int total = NWd3 + NWr + NWs;
    const int stride = gridDim.x * blockDim.x;
    for (int i = blockIdx.x * blockDim.x + threadIdx.x; i < total; i += stride) {
        if (i < NWd3) {
            const int ci = i & 511;
            int t2 = i >> 9;
            const int co = t2 & 1023;
            const int l = t2 >> 10;
            const float* src = dil_w + (size_t)i * 3;   // i = (l*1024+co)*512+ci
            #pragma unroll
            for (int tap = 0; tap < 3; ++tap) {
                const float w = src[tap];
                const size_t d = ((size_t)(l * 3 + tap) * 1024 + co) * 512 + ci;
                const unsigned short h = bf16rne(w);
                WdH[d] = h;
                if (split) WdL[d] = bf16rne(w - bf2f(h));
            }
        } else if (i < NWd3 + NWr) {
            const int j2 = i - NWd3;
            const float w = res_w[j2];
            const unsigned short h = bf16rne(w);
            WrH[j2] = h;
            if (split) WrL[j2] = bf16rne(w - bf2f(h));
        } else {
            const int j2 = i - NWd3 - NWr;
            const float w = skip_w[j2];
            const unsigned short h = bf16rne(w);
            WsH[j2] = h;
            if (split) WsL[j2] = bf16rne(w - bf2f(h));
        }
    }
}

// ---------------- init: x0 = start_conv(audio) + mel_conv(mel) -------------
__global__ __launch_bounds__(512)
void k_init(const float* __restrict__ audio, const float* __restrict__ mel,
            const float* __restrict__ start_w, const float* __restrict__ start_b,
            const float* __restrict__ mel_w, const float* __restrict__ mel_b,
            float* __restrict__ x0,
            unsigned short* __restrict__ xH, unsigned short* __restrict__ xL,
            float* __restrict__ skip_acc, int split)
{
    __shared__ float smel[MEL_C][64];
    __shared__ float sa[64];
    const int tid = threadIdx.x;
    const int b = blockIdx.x >> 7;             // 128 tiles per batch
    const int t0 = (blockIdx.x & 127) << 6;
    for (int i = tid; i < MEL_C * 64; i += 512) {
        const int m = i >> 6, tt = i & 63;
        smel[m][tt] = mel[((size_t)b * MEL_C + m) * TB + t0 + tt];
    }
    if (tid < 64) sa[tid] = audio[(size_t)b * TB + t0 + tid];
    for (int i = tid; i < 64 * SKIP_C; i += 512) {
        const int tt = i >> 8, c = i & 255;
        skip_acc[(size_t)(b * TB + t0 + tt) * SKIP_C + c] = 0.f;
    }
    __syncthreads();
    const int c = tid;                          // 512 channels
    const float sw = start_w[c];
    const float bias = start_b[c] + mel_b[c];
    const float* wrow = mel_w + (size_t)c * MEL_C;
    v4f acc[16];
    #pragma unroll
    for (int q = 0; q < 16; ++q) {
        v4f av = *(const v4f*)&sa[q * 4];
        acc[q][0] = fmaf(sw, av[0], bias);
        acc[q][1] = fmaf(sw, av[1], bias);
        acc[q][2] = fmaf(sw, av[2], bias);
        acc[q][3] = fmaf(sw, av[3], bias);
    }
    for (int m = 0; m < MEL_C; ++m) {
        const float w = wrow[m];
        #pragma unroll
        for (int q = 0; q < 16; ++q) {
            v4f mv = *(const v4f*)&smel[m][q * 4];
            acc[q][0] = fmaf(w, mv[0], acc[q][0]);
            acc[q][1] = fmaf(w, mv[1], acc[q][1]);
            acc[q][2] = fmaf(w, mv[2], acc[q][2]);
            acc[q][3] = fmaf(w, mv[3], acc[q][3]);
        }
    }
    #pragma unroll
    for (int q = 0; q < 16; ++q) {
        #pragma unroll
        for (int e = 0; e < 4; ++e) {
            const int tt = q * 4 + e;
            const size_t o = (size_t)(b * TB + t0 + tt) * RES_C + c;
            const float v = acc[q][e];
            x0[o] = v;
            const unsigned short h = bf16rne(v);
            xH[o] = h;
            if (split) xL[o] = bf16rne(v - bf2f(h));
        }
    }
}

// ---------------- K1: a = tanh(f)*sigmoid(g), f,g = dilated conv -----------
// grid 512: XCD-aware mapping. Each block: 64-t tile x 256 cout (p half).
// Even XCDs take p=0, odd p=1 -> per-XCD weight working set 3.15 MB < 4 MB L2.
// 2-phase pipeline: double-buffered 64 KB LDS -> 2 blocks/CU (4 waves/SIMD).
__global__ __launch_bounds__(512)
void k1_dilgate(const unsigned short* __restrict__ xH,
                const unsigned short* __restrict__ xL,
                unsigned short* __restrict__ aH, unsigned short* __restrict__ aL,
                const unsigned short* __restrict__ WdH,  // [3][1024][512] this layer
                const unsigned short* __restrict__ WdL,
                const float* __restrict__ dil_b,         // [1024] this layer
                int dil, int split)
{
    __shared__ unsigned short shb2[2][64 * 128];    // [buf][t 64][k 128] bf16 hi, XOR-swizzled
    __shared__ unsigned short slb2[2][64 * 128];    // lo
    const int tid = threadIdx.x;
    const int wave = tid >> 6, lane = tid & 63;
    const int quad = lane >> 4, l15 = lane & 15;
    // XCD-aware decomposition of 512 blocks: xcd = idx&7 (HW round-robin),
    // p = xcd parity, t-quarter = xcd>>1, 64 tiles per quarter.
    const int idx = blockIdx.x;
    const int xcd = idx & 7;
    const int j64 = idx >> 3;            // 0..63
    const int p = xcd & 1;
    const int tl = (xcd >> 1) * 64 + j64;   // 0..255 (b*128 + tile)
    const int b = tl >> 7;
    const int t0 = (tl & 127) << 6;
    const int fbase = p * 256 + wave * 32;
    const int srow = lane >> 4;          // 0..3 within a 4-row staging call
    const int schunk = lane & 15;        // 16B chunk within row

    const v4f vz = {0.f, 0.f, 0.f, 0.f};
    v4f accF[2][4], accG[2][4];
    #pragma unroll
    for (int mt = 0; mt < 2; ++mt)
        #pragma unroll
        for (int n = 0; n < 4; ++n) { accF[mt][n] = vz; accG[mt][n] = vz; }

    // stage chunk (tap = chunk>>2, ks = chunk&3) into buffer buf.
    // LDS content at (row r, chunk c) = global 16B chunk c ^ (r&7) (involution,
    // matches reader's nsw). gload_lds dest is linear: base + lane*16.
    auto stage = [&](int chunk, int buf) {
        const int tap = chunk >> 2, ks = chunk & 3;
        const int off = (tap - 1) * dil;
        const bool allok = (t0 + off >= 0) && (t0 + 63 + off < TB);  // block-uniform
        unsigned short* dsth = shb2[buf];
        unsigned short* dstl = slb2[buf];
        if (allok) {
            #pragma unroll
            for (int q = 0; q < 2; ++q) {
                const int rbase = wave * 8 + q * 4;
                const int r = rbase + srow;
                const size_t go = (size_t)(b * TB + t0 + r + off) * RES_C
                                + ks * 128 + ((schunk ^ (r & 7)) << 3);
                gld16(xH + go, dsth + rbase * 128);
                if (split) gld16(xL + go, dstl + rbase * 128);
            }
        } else {
            #pragma unroll
            for (int q = 0; q < 2; ++q) {
                const int rbase = wave * 8 + q * 4;
                const int r = rbase + srow;
                const int tsrc = t0 + r + off;
                const bool ok = (unsigned)tsrc < TB;
                const size_t go = (size_t)(b * TB + tsrc) * RES_C
                                + ks * 128 + ((schunk ^ (r & 7)) << 3);
                v8u16 vh = ok ? *(const v8u16*)(xH + go) : (v8u16)0;
                *(v8u16*)(dsth + rbase * 128 + (lane << 3)) = vh;
                if (split) {
                    v8u16 vl = ok ? *(const v8u16*)(xL + go) : (v8u16)0;
                    *(v8u16*)(dstl + rbase * 128 + (lane << 3)) = vl;
                }
            }
        }
    };

    auto compute = [&](int chunk, int buf) {
        const int tap = chunk >> 2, ks = chunk & 3;
        const unsigned short* WHT = WdH + (size_t)tap * 1024 * 512;
        const unsigned short* WLT = WdL + (size_t)tap * 1024 * 512;
        const unsigned short* shb = shb2[buf];
        const unsigned short* slb = slb2[buf];
        #pragma unroll
        for (int kc = 0; kc < 4; ++kc) {
            const int kg = ks * 128 + kc * 32 + quad * 8;
            v8s afh[2], agh[2], afl[2], agl[2];
            #pragma unroll
            for (int mt = 0; mt < 2; ++mt) {
                const int row = fbase + mt * 16 + l15;
                afh[mt] = *(const v8s*)(WHT + (size_t)row * 512 + kg);
                agh[mt] = *(const v8s*)(WHT + (size_t)(row + 512) * 512 + kg);
                if (split) {
                    afl[mt] = *(const v8s*)(WLT + (size_t)row * 512 + kg);
                    agl[mt] = *(const v8s*)(WLT + (size_t)(row + 512) * 512 + kg);
                }
            }
            const int nsw = ((kc * 4 + quad) ^ (l15 & 7)) << 3;
            v8s bh[4], bl[4];
            #pragma unroll
            for (int j = 0; j < 4; ++j) {
                const int trow = j * 16 + l15;
                bh[j] = *(const v8s*)(shb + trow * 128 + nsw);
                if (split) bl[j] = *(const v8s*)(slb + trow * 128 + nsw);
            }
            #pragma unroll
            for (int mt = 0; mt < 2; ++mt)
                #pragma unroll
                for (int j = 0; j < 4; ++j) {
                    accF[mt][j] = __builtin_amdgcn_mfma_f32_16x16x32_bf16(
                        afh[mt], bh[j], accF[mt][j], 0, 0, 0);
                    accG[mt][j] = __builtin_amdgcn_mfma_f32_16x16x32_bf16(
                        agh[mt], bh[j], accG[mt][j], 0, 0, 0);
                    if (split) {
                        accF[mt][j] = __builtin_amdgcn_mfma_f32_16x16x32_bf16(
                            afh[mt], bl[j], accF[mt][j], 0, 0, 0);
                        accF[mt][j] = __builtin_amdgcn_mfma_f32_16x16x32_bf16(
                            afl[mt], bh[j], accF[mt][j], 0, 0, 0);
                        accG[mt][j] = __builtin_amdgcn_mfma_f32_16x16x32_bf16(
                            agh[mt], bl[j], accG[mt][j], 0, 0, 0);
                        accG[mt][j] = __builtin_amdgcn_mfma_f32_16x16x32_bf16(
                            agl[mt], bh[j], accG[mt][j], 0, 0, 0);
                    }
                }
        }
    };

    stage(0, 0);
    __syncthreads();                       // drain prologue stage
    for (int chunk = 0; chunk < 12; ++chunk) {
        if (chunk < 11) stage(chunk + 1, (chunk + 1) & 1);  // async, other buffer
        compute(chunk, chunk & 1);
        __syncthreads();                   // vmcnt(0)+lgkmcnt(0)+barrier: next buf ready
    }

    // gate epilogue: f,g tiles share C-layout -> in-register gating
    unsigned short* aHb = aH + (size_t)b * TB * RES_C;
    unsigned short* aLb = aL + (size_t)b * TB * RES_C;
    #pragma unroll
    for (int mt = 0; mt < 2; ++mt) {
        const int ch = p * 256 + wave * 32 + mt * 16 + quad * 4;
        const float4 bF = *(const float4*)(dil_b + ch);
        const float4 bG = *(const float4*)(dil_b + 512 + ch);
        #pragma unroll
        for (int n = 0; n < 4; ++n) {
            const int t = t0 + n * 16 + l15;
            float a0 = ftanh_(accF[mt][n][0] + bF.x) * fsigmoid(accG[mt][n][0] + bG.x);
            float a1 = ftanh_(accF[mt][n][1] + bF.y) * fsigmoid(accG[mt][n][1] + bG.y);
            float a2 = ftanh_(accF[mt][n][2] + bF.z) * fsigmoid(accG[mt][n][2] + bG.z);
            float a3 = ftanh_(accF[mt][n][3] + bF.w) * fsigmoid(accG[mt][n][3] + bG.w);
            v4u16 oh;
            oh[0] = bf16rne(a0); oh[1] = bf16rne(a1);
            oh[2] = bf16rne(a2); oh[3] = bf16rne(a3);
            *(v4u16*)(aHb + (size_t)t * RES_C + ch) = oh;
            if (split) {
                v4u16 ol;
                ol[0] = bf16rne(a0 - bf2f(oh[0]));
                ol[1] = bf16rne(a1 - bf2f(oh[1]));
                ol[2] = bf16rne(a2 - bf2f(oh[2]));
                ol[3] = bf16rne(a3 - bf2f(oh[3]));
                *(v4u16*)(aLb + (size_t)t * RES_C + ch) = ol;
            }
        }
    }
}

// ---------------- K3: x += res(a) (in place); skip += skipconv(a) ----------
// grid 512 = b(2) x 256 time-tiles of 32; 48 M-tiles over 8 waves
__global__ __launch_bounds__(512)
void k3_resskip(float* __restrict__ x,
                unsigned short* __restrict__ xH, unsigned short* __restrict__ xL,
                float* __restrict__ skip_acc,
                const unsigned short* __restrict__ aH,
                const unsigned short* __restrict__ aL,
                const unsigned short* __restrict__ WrH, const unsigned short* __restrict__ WrL,
                const unsigned short* __restrict__ WsH, const unsigned short* __restrict__ WsL,
                const float* __restrict__ res_b, const float* __restrict__ skip_b,
                int split)
{
    __shared__ unsigned short shi[32 * 512];    // [t 32][c 512] bf16, swizzled
    __shared__ unsigned short slo[32 * 512];
    const int tid = threadIdx.x;
    const int wave = tid >> 6, lane = tid & 63;
    const int quad = lane >> 4, l15 = lane & 15;
    const int b = blockIdx.x >> 8;
    const int t0 = (blockIdx.x & 255) << 5;
    {
        // gload_lds staging: one full 1KB row per wave-call; content at chunk c
        // is global chunk c^(r&7) (matches reader's nsw XOR)
        #pragma unroll
        for (int q = 0; q < 4; ++q) {
            const int r = wave * 4 + q;
            const size_t go = (size_t)(b * TB + t0 + r) * RES_C + ((lane ^ (r & 7)) << 3);
            gld16(aH + go, shi + r * 512);
            if (split) gld16(aL + go, slo + r * 512);
        }
    }
    __syncthreads();
    const v4f vz = {0.f, 0.f, 0.f, 0.f};
    v4f acc[6][2];
    #pragma unroll
    for (int i = 0; i < 6; ++i) { acc[i][0] = vz; acc[i][1] = vz; }

    for (int kc = 0; kc < 16; ++kc) {
        const int k0 = kc * 32 + quad * 8;
        const int nsw = ((kc * 4 + quad) ^ (l15 & 7)) << 3;
        v8s bh[2], bl[2];
        #pragma unroll
        for (int j = 0; j < 2; ++j) {
            bh[j] = *(const v8s*)(shi + (j * 16 + l15) * 512 + nsw);
            if (split) bl[j] = *(const v8s*)(slo + (j * 16 + l15) * 512 + nsw);
        }
        #pragma unroll
        for (int i = 0; i < 6; ++i) {
            const int row = (wave * 6 + i) * 16 + l15;
            v8s ah, al;
            if (row < 512) {
                ah = *(const v8s*)(WrH + (size_t)row * 512 + k0);
                if (split) al = *(const v8s*)(WrL + (size_t)row * 512 + k0);
            } else {
                ah = *(const v8s*)(WsH + (size_t)(row - 512) * 512 + k0);
                if (split) al = *(const v8s*)(WsL + (size_t)(row - 512) * 512 + k0);
            }
            #pragma unroll
            for (int j = 0; j < 2; ++j) {
                acc[i][j] = __builtin_amdgcn_mfma_f32_16x16x32_bf16(ah, bh[j], acc[i][j], 0, 0, 0);
                if (split) {
                    acc[i][j] = __builtin_amdgcn_mfma_f32_16x16x32_bf16(ah, bl[j], acc[i][j], 0, 0, 0);
                    acc[i][j] = __builtin_amdgcn_mfma_f32_16x16x32_bf16(al, bh[j], acc[i][j], 0, 0, 0);
                }
            }
        }
    }
    #pragma unroll
    for (int i = 0; i < 6; ++i) {
        const int rb = (wave * 6 + i) * 16 + quad * 4;
        if (rb < 512) {
            const float4 bias = *(const float4*)(res_b + rb);
            #pragma unroll
            for (int j = 0; j < 2; ++j) {
                const int t = t0 + j * 16 + l15;
                const size_t o = (size_t)(b * TB + t) * RES_C + rb;
                float4 v = *(const float4*)(x + o);
                v.x += acc[i][j][0] + bias.x;
                v.y += acc[i][j][1] + bias.y;
                v.z += acc[i][j][2] + bias.z;
                v.w += acc[i][j][3] + bias.w;
                *(float4*)(x + o) = v;
                v4u16 oh;
                oh[0] = bf16rne(v.x); oh[1] = bf16rne(v.y);
                oh[2] = bf16rne(v.z); oh[3] = bf16rne(v.w);
                *(v4u16*)(xH + o) = oh;
                if (split) {
                    v4u16 ol;
                    ol[0] = bf16rne(v.x - bf2f(oh[0]));
                    ol[1] = bf16rne(v.y - bf2f(oh[1]));
                    ol[2] = bf16rne(v.z - bf2f(oh[2]));
                    ol[3] = bf16rne(v.w - bf2f(oh[3]));
                    *(v4u16*)(xL + o) = ol;
                }
            }
        } else {
            const int rs = rb - 512;
            const float4 bias = *(const float4*)(skip_b + rs);
            #pragma unroll
            for (int j = 0; j < 2; ++j) {
                const int t = t0 + j * 16 + l15;
                const size_t o = (size_t)(b * TB + t) * SKIP_C + rs;
                float4 v = *(const float4*)(skip_acc + o);
                v.x += acc[i][j][0] + bias.x;
                v.y += acc[i][j][1] + bias.y;
                v.z += acc[i][j][2] + bias.z;
                v.w += acc[i][j][3] + bias.w;
                *(float4*)(skip_acc + o) = v;
            }
        }
    }
}

// ---------------- final: out = tanh(fc2(relu(fc1(skip)))) ------------------
__global__ __launch_bounds__(256)
void k4_final(const float* __restrict__ skip_acc,
              const float* __restrict__ fc1_w, const float* __restrict__ fc1_b,
              const float* __restrict__ fc2_w, const float* __restrict__ fc2_b,
              float* __restrict__ out)
{
    __shared__ float stile[32 * 260];   // [t 32][c 256] fp32, row pad 4
    __shared__ float part[8][32];
    const int tid = threadIdx.x;
    const int b = blockIdx.x >> 8;
    const int t0 = (blockIdx.x & 255) << 5;
    {
        const int r = tid >> 3, sub = tid & 7;
        const float* srow = skip_acc + (size_t)(b * TB + t0 + r) * SKIP_C;
        float* drow = stile + r * 260;
        #pragma unroll
        for (int i = 0; i < 8; ++i) {
            const int c = (i * 8 + sub) * 4;
            *(float4*)(drow + c) = *(const float4*)(srow + c);
        }
    }
    __syncthreads();
    const int t = tid & 31;
    const int w = tid >> 5;             // 8 groups of 32 cout
    float y[32];
    #pragma unroll
    for (int co = 0; co < 32; ++co) y[co] = fc1_b[w * 32 + co];
    const float* srow = stile + t * 260;
    for (int ci = 0; ci < SKIP_C; ++ci) {
        const float s = srow[ci];
        const float* wcol = fc1_w + (size_t)(w * 32) * SKIP_C + ci;
        #pragma unroll
        for (int co = 0; co < 32; ++co)
            y[co] = fmaf(wcol[(size_t)co * SKIP_C], s, y[co]);
    }
    float partial = 0.f;
    #pragma unroll
    for (int co = 0; co < 32; ++co) {
        const float v = y[co] > 0.f ? y[co] : 0.f;
        partial = fmaf(fc2_w[w * 32 + co], v, partial);
    }
    part[w][t] = partial;
    __syncthreads();
    if (tid < 32) {
        float v = fc2_b[0];
        #pragma unroll
        for (int k = 0; k < 8; ++k) v += part[k][tid];
        out[(size_t)b * TB + t0 + tid] = ftanh_(v);
    }
}

// ---------------- host ----------------
extern "C" void kernel_launch(void* const* d_in, const int* in_sizes, int n_in,
                              void* d_out, int out_size, void* d_ws, size_t ws_size,
                              hipStream_t stream)
{
    const float* mel     = (const float*)d_in[0];
    const float* audio   = (const float*)d_in[1];
    const float* start_w = (const float*)d_in[2];
    const float* start_b = (const float*)d_in[3];
    const float* mel_w   = (const float*)d_in[4];
    const float* mel_b   = (const float*)d_in[5];
    const float* dil_b   = (const float*)d_in[7];
    const float* res_b   = (const float*)d_in[9];
    const float* skip_b  = (const float*)d_in[11];
    const float* fc1_w   = (const float*)d_in[12];
    const float* fc1_b   = (const float*)d_in[13];
    const float* fc2_w   = (const float*)d_in[14];
    const float* fc2_b   = (const float*)d_in[15];
    float* out = (float*)d_out;

    char* ws = (char*)d_ws;
    const size_t szWd = (size_t)NLAYERS * 3 * 1024 * 512 * 2;  // 94.4 MB
    const size_t szWr = (size_t)NLAYERS * 512 * 512 * 2;       // 15.7 MB
    const size_t szWs = (size_t)NLAYERS * 256 * 512 * 2;       //  7.9 MB
    const size_t szX32 = (size_t)NBATCH * TB * RES_C * 4;      // 33.6 MB
    const size_t szX16 = (size_t)NBATCH * TB * RES_C * 2;      // 16.8 MB
    const size_t szSk = (size_t)NBATCH * TB * SKIP_C * 4;      // 16.8 MB
    size_t off = 0;
    unsigned short* WdH = (unsigned short*)(ws + off); off += szWd;
    unsigned short* WrH = (unsigned short*)(ws + off); off += szWr;
    unsigned short* WsH = (unsigned short*)(ws + off); off += szWs;
    float* x = (float*)(ws + off); off += szX32;
    unsigned short* xH = (unsigned short*)(ws + off); off += szX16;
    unsigned short* aH = (unsigned short*)(ws + off); off += szX16;
    float* skip_acc = (float*)(ws + off); off += szSk;
    const size_t lo_need = szX16 * 2 + szWd + szWr + szWs;
    const int split = (off + lo_need <= ws_size) ? 1 : 0;
    unsigned short* xL = split ? (unsigned short*)(ws + off) : xH; if (split) off += szX16;
    unsigned short* aL = split ? (unsigned short*)(ws + off) : aH; if (split) off += szX16;
    unsigned short* WdL = split ? (unsigned short*)(ws + off) : WdH; if (split) off += szWd;
    unsigned short* WrL = split ? (unsigned short*)(ws + off) : WrH; if (split) off += szWr;
    unsigned short* WsL = split ? (unsigned short*)(ws + off) : WsH; if (split) off += szWs;

    k0_pack<<<8192, 256, 0, stream>>>((const float*)d_in[6], (const float*)d_in[8],
                                      (const float*)d_in[10],
                                      WdH, WdL, WrH, WrL, WsH, WsL, split);
    k_init<<<NBATCH * (TB / 64), 512, 0, stream>>>(
        audio, mel, start_w, start_b, mel_w, mel_b, x, xH, xL, skip_acc, split);

    for (int l = 0; l < NLAYERS; ++l) {
        const int dil = 1 << (l % 10);
        k1_dilgate<<<512, 512, 0, stream>>>(xH, xL, aH, aL,
            WdH + (size_t)l * 3 * 1024 * 512, WdL + (size_t)l * 3 * 1024 * 512,
            dil_b + (size_t)l * 1024, dil, split);
        k3_resskip<<<512, 512, 0, stream>>>(x, xH, xL, skip_acc, aH, aL,
            WrH + (size_t)l * 512 * 512, WrL + (size_t)l * 512 * 512,
            WsH + (size_t)l * 256 * 512, WsL + (size_t)l * 256 * 512,
            res_b + (size_t)l * 512, skip_b + (size_t)l * 256, split);
    }
    k4_final<<<512, 256, 0, stream>>>(skip_acc, fc1_w, fc1_b, fc2_w, fc2_b, out);
}

// Round 3
// 7253.234 us; speedup vs baseline: 1.4860x; 1.4860x over previous
//
#include <hip/hip_runtime.h>
#include <stdint.h>

#define TB 8192
#define NBATCH 2
#define RES_C 512
#define SKIP_C 256
#define MEL_C 80
#define NLAYERS 30

typedef short v8s __attribute__((ext_vector_type(8)));
typedef float v4f __attribute__((ext_vector_type(4)));
typedef unsigned short v4u16 __attribute__((ext_vector_type(4)));
typedef unsigned short v8u16 __attribute__((ext_vector_type(8)));

__device__ __forceinline__ unsigned short bf16rne(float f) {
    unsigned u = __float_as_uint(f);
    return (unsigned short)((u + 0x7fffu + ((u >> 16) & 1u)) >> 16);
}
__device__ __forceinline__ float bf2f(unsigned short h) {
    return __uint_as_float((unsigned)h << 16);
}
__device__ __forceinline__ float fsigmoid(float x) { return 1.0f / (1.0f + __expf(-x)); }
__device__ __forceinline__ float ftanh_(float x) { return 2.0f / (1.0f + __expf(-2.0f * x)) - 1.0f; }

// async 16B global->LDS (linear dest: wave-uniform base + lane*16)
__device__ __forceinline__ void gld16(const void* g, void* l) {
    __builtin_amdgcn_global_load_lds(
        (const __attribute__((address_space(1))) unsigned int*)g,
        (__attribute__((address_space(3))) unsigned int*)l, 16, 0, 0);
}

// ---------------- prep: pack weights fragment-major ----------------
// Wp layout (per layer): frag idx = (p*8+wv)*192 + ((tap*4+ks)*16 + kc*4 + mt*2 + fg),
// each frag expanded by TC tiers (H, then L), frag body = [lane 64][8 bf16] = 1KB.
// A k1 wave reads its 384KB (TC=2) as a pure sequential stream, 1KB coalesced/load.
// Wq layout (per layer): frag idx = wv*96 + kc*6 + i6 (rows (wv*6+i6)*16+l15, combined
// res rows 0..511 / skip rows 512..767), TC tiers, same 1KB frag body.
__global__ void k0_pack(const float* __restrict__ dil_w,
                        const float* __restrict__ res_w,
                        const float* __restrict__ skip_w,
                        unsigned short* __restrict__ Wp,
                        unsigned short* __restrict__ Wq,
                        int split)
{
    const int TC = split + 1;
    const int NWd3 = NLAYERS * 1024 * 512;   // dil triples
    const int NWr = NLAYERS * 512 * 512;
    const int NWs = NLAYERS * 256 * 512;
    const int total = NWd3 + NWr + NWs;
    const int stride = gridDim.x * blockDim.x;
    for (int i = blockIdx.x * blockDim.x + threadIdx.x; i < total; i += stride) {
        if (i < NWd3) {
            const int ci = i & 511;
            int t2 = i >> 9;
            const int co = t2 & 1023;
            const int l = t2 >> 10;
            const int fg = co >> 9, r = co & 511;
            const int p = r >> 8, wv = (r >> 5) & 7, mt = (r >> 4) & 1, l15 = r & 15;
            const int ks = ci >> 7, kc = (ci >> 5) & 3, quad = (ci >> 3) & 3, e = ci & 7;
            const int lane = quad * 16 + l15;
            const float* src = dil_w + (size_t)i * 3;   // i = (l*1024+co)*512+ci
            unsigned short* lbase = Wp + (size_t)l * 3072 * TC * 512;
            #pragma unroll
            for (int tap = 0; tap < 3; ++tap) {
                const float w = src[tap];
                const int idx = ((p * 8 + wv) * 192
                               + ((tap * 4 + ks) * 16 + kc * 4 + mt * 2 + fg)) * TC;
                unsigned short* d = lbase + (size_t)idx * 512 + lane * 8 + e;
                const unsigned short h = bf16rne(w);
                d[0] = h;
                if (split) d[512] = bf16rne(w - bf2f(h));
            }
        } else {
            int rowc, ci, l;
            float w;
            if (i < NWd3 + NWr) {
                const int j2 = i - NWd3;
                l = j2 >> 18; rowc = (j2 >> 9) & 511; ci = j2 & 511;
                w = res_w[j2];
            } else {
                const int j2 = i - NWd3 - NWr;
                l = j2 >> 17; rowc = ((j2 >> 9) & 255) + 512; ci = j2 & 511;
                w = skip_w[j2];
            }
            const int rowgrp = rowc >> 4, l15 = rowc & 15;
            const int wv = rowgrp / 6, i6 = rowgrp % 6;
            const int kc = ci >> 5, quad = (ci >> 3) & 3, e = ci & 7;
            const int lane = quad * 16 + l15;
            const int idx = (wv * 96 + kc * 6 + i6) * TC;
            unsigned short* d = Wq + (size_t)l * 768 * TC * 512 + (size_t)idx * 512
                              + lane * 8 + e;
            const unsigned short h = bf16rne(w);
            d[0] = h;
            if (split) d[512] = bf16rne(w - bf2f(h));
        }
    }
}

// ---------------- init: x0 = start_conv(audio) + mel_conv(mel) -------------
__global__ __launch_bounds__(512)
void k_init(const float* __restrict__ audio, const float* __restrict__ mel,
            const float* __restrict__ start_w, const float* __restrict__ start_b,
            const float* __restrict__ mel_w, const float* __restrict__ mel_b,
            float* __restrict__ x0,
            unsigned short* __restrict__ xH, unsigned short* __restrict__ xL,
            float* __restrict__ skip_acc, int split)
{
    __shared__ float smel[MEL_C][64];
    __shared__ float sa[64];
    const int tid = threadIdx.x;
    const int b = blockIdx.x >> 7;             // 128 tiles per batch
    const int t0 = (blockIdx.x & 127) << 6;
    for (int i = tid; i < MEL_C * 64; i += 512) {
        const int m = i >> 6, tt = i & 63;
        smel[m][tt] = mel[((size_t)b * MEL_C + m) * TB + t0 + tt];
    }
    if (tid < 64) sa[tid] = audio[(size_t)b * TB + t0 + tid];
    for (int i = tid; i < 64 * SKIP_C; i += 512) {
        const int tt = i >> 8, c = i & 255;
        skip_acc[(size_t)(b * TB + t0 + tt) * SKIP_C + c] = 0.f;
    }
    __syncthreads();
    const int c = tid;                          // 512 channels
    const float sw = start_w[c];
    const float bias = start_b[c] + mel_b[c];
    const float* wrow = mel_w + (size_t)c * MEL_C;
    v4f acc[16];
    #pragma unroll
    for (int q = 0; q < 16; ++q) {
        v4f av = *(const v4f*)&sa[q * 4];
        acc[q][0] = fmaf(sw, av[0], bias);
        acc[q][1] = fmaf(sw, av[1], bias);
        acc[q][2] = fmaf(sw, av[2], bias);
        acc[q][3] = fmaf(sw, av[3], bias);
    }
    for (int m = 0; m < MEL_C; ++m) {
        const float w = wrow[m];
        #pragma unroll
        for (int q = 0; q < 16; ++q) {
            v4f mv = *(const v4f*)&smel[m][q * 4];
            acc[q][0] = fmaf(w, mv[0], acc[q][0]);
            acc[q][1] = fmaf(w, mv[1], acc[q][1]);
            acc[q][2] = fmaf(w, mv[2], acc[q][2]);
            acc[q][3] = fmaf(w, mv[3], acc[q][3]);
        }
    }
    #pragma unroll
    for (int q = 0; q < 16; ++q) {
        #pragma unroll
        for (int e = 0; e < 4; ++e) {
            const int tt = q * 4 + e;
            const size_t o = (size_t)(b * TB + t0 + tt) * RES_C + c;
            const float v = acc[q][e];
            x0[o] = v;
            const unsigned short h = bf16rne(v);
            xH[o] = h;
            if (split) xL[o] = bf16rne(v - bf2f(h));
        }
    }
}

// ---------------- K1: a = tanh(f)*sigmoid(g), f,g = dilated conv -----------
// grid 256 = 128 time-tiles(128 wide) x 2 channel-chunks(p); p aligns with XCD
// parity (idx&1) so each XCD's L2 holds one 3.15MB weight half.
// Weights consumed as a sequential per-wave fragment stream (Wp layout).
__global__ __launch_bounds__(512)
void k1_dilgate(const unsigned short* __restrict__ xH,
                const unsigned short* __restrict__ xL,
                unsigned short* __restrict__ aH, unsigned short* __restrict__ aL,
                const unsigned short* __restrict__ Wp,   // this layer, frag-major
                const float* __restrict__ dil_b,         // [1024] this layer
                int dil, int split)
{
    __shared__ unsigned short shb2[2][128 * 128];   // [buf][t 128][k 128] bf16 hi, swizzled
    __shared__ unsigned short slb2[2][128 * 128];   // lo
    const int TC = split + 1;
    const int tid = threadIdx.x;
    const int wave = tid >> 6, lane = tid & 63;
    const int quad = lane >> 4, l15 = lane & 15;
    const int p = blockIdx.x & 1;
    const int tl = blockIdx.x >> 1;
    const int b = tl >> 6;
    const int t0 = (tl & 63) << 7;
    const int srow = lane >> 4;          // 0..3 within a 4-row staging call
    const int schunk = lane & 15;        // 16B chunk within row
    // per-wave weight stream base (frag stride 512 shorts = 1KB)
    const unsigned short* wpw = Wp + ((size_t)(p * 8 + wave) * 192 * TC) * 512 + lane * 8;

    const v4f vz = {0.f, 0.f, 0.f, 0.f};
    v4f accF[2][8], accG[2][8];
    #pragma unroll
    for (int mt = 0; mt < 2; ++mt)
        #pragma unroll
        for (int n = 0; n < 8; ++n) { accF[mt][n] = vz; accG[mt][n] = vz; }

    auto stage = [&](int chunk, int buf) {
        const int tap = chunk >> 2, ks = chunk & 3;
        const int off = (tap - 1) * dil;
        const bool allok = (t0 + off >= 0) && (t0 + 127 + off < TB);  // block-uniform
        unsigned short* dsth = shb2[buf];
        unsigned short* dstl = slb2[buf];
        if (allok) {
            #pragma unroll
            for (int q = 0; q < 4; ++q) {
                const int rbase = wave * 16 + q * 4;
                const int r = rbase + srow;
                const size_t go = (size_t)(b * TB + t0 + r + off) * RES_C
                                + ks * 128 + ((schunk ^ (r & 7)) << 3);
                gld16(xH + go, dsth + rbase * 128);
                if (split) gld16(xL + go, dstl + rbase * 128);
            }
        } else {
            #pragma unroll
            for (int q = 0; q < 4; ++q) {
                const int rbase = wave * 16 + q * 4;
                const int r = rbase + srow;
                const int tsrc = t0 + r + off;
                const bool ok = (unsigned)tsrc < TB;
                const size_t go = (size_t)(b * TB + tsrc) * RES_C
                                + ks * 128 + ((schunk ^ (r & 7)) << 3);
                v8u16 vh = ok ? *(const v8u16*)(xH + go) : (v8u16)0;
                *(v8u16*)(dsth + rbase * 128 + (lane << 3)) = vh;
                if (split) {
                    v8u16 vl = ok ? *(const v8u16*)(xL + go) : (v8u16)0;
                    *(v8u16*)(dstl + rbase * 128 + (lane << 3)) = vl;
                }
            }
        }
    };

    auto compute = [&](int chunk, int buf) {
        const int tap = chunk >> 2, ks = chunk & 3;
        const unsigned short* cb = wpw + (size_t)((tap * 4 + ks) * 16) * TC * 512;
        const unsigned short* shb = shb2[buf];
        const unsigned short* slb = slb2[buf];
        #pragma unroll
        for (int kc = 0; kc < 4; ++kc) {
            const unsigned short* ck = cb + (size_t)(kc * 4) * TC * 512;
            v8s afh[2], agh[2], afl[2], agl[2];
            #pragma unroll
            for (int mt = 0; mt < 2; ++mt) {
                afh[mt] = *(const v8s*)(ck + (size_t)((mt * 2 + 0) * TC) * 512);
                agh[mt] = *(const v8s*)(ck + (size_t)((mt * 2 + 1) * TC) * 512);
                if (split) {
                    afl[mt] = *(const v8s*)(ck + (size_t)((mt * 2 + 0) * TC + 1) * 512);
                    agl[mt] = *(const v8s*)(ck + (size_t)((mt * 2 + 1) * TC + 1) * 512);
                }
            }
            const int nsw = ((kc * 4 + quad) ^ (l15 & 7)) << 3;
            #pragma unroll
            for (int nh = 0; nh < 2; ++nh) {
                v8s bh[4], bl[4];
                #pragma unroll
                for (int j = 0; j < 4; ++j) {
                    const int trow = (nh * 4 + j) * 16 + l15;
                    bh[j] = *(const v8s*)(shb + trow * 128 + nsw);
                    if (split) bl[j] = *(const v8s*)(slb + trow * 128 + nsw);
                }
                #pragma unroll
                for (int mt = 0; mt < 2; ++mt)
                    #pragma unroll
                    for (int j = 0; j < 4; ++j) {
                        const int n = nh * 4 + j;
                        accF[mt][n] = __builtin_amdgcn_mfma_f32_16x16x32_bf16(
                            afh[mt], bh[j], accF[mt][n], 0, 0, 0);
                        accG[mt][n] = __builtin_amdgcn_mfma_f32_16x16x32_bf16(
                            agh[mt], bh[j], accG[mt][n], 0, 0, 0);
                        if (split) {
                            accF[mt][n] = __builtin_amdgcn_mfma_f32_16x16x32_bf16(
                                afh[mt], bl[j], accF[mt][n], 0, 0, 0);
                            accF[mt][n] = __builtin_amdgcn_mfma_f32_16x16x32_bf16(
                                afl[mt], bh[j], accF[mt][n], 0, 0, 0);
                            accG[mt][n] = __builtin_amdgcn_mfma_f32_16x16x32_bf16(
                                agh[mt], bl[j], accG[mt][n], 0, 0, 0);
                            accG[mt][n] = __builtin_amdgcn_mfma_f32_16x16x32_bf16(
                                agl[mt], bh[j], accG[mt][n], 0, 0, 0);
                        }
                    }
            }
        }
    };

    stage(0, 0);
    __syncthreads();                       // drain prologue stage
    for (int chunk = 0; chunk < 12; ++chunk) {
        if (chunk < 11) stage(chunk + 1, (chunk + 1) & 1);  // async, other buffer
        compute(chunk, chunk & 1);
        __syncthreads();                   // vmcnt(0)+lgkmcnt(0)+barrier: next buf ready
    }

    // gate epilogue: f,g tiles share C-layout -> in-register gating
    unsigned short* aHb = aH + (size_t)b * TB * RES_C;
    unsigned short* aLb = aL + (size_t)b * TB * RES_C;
    #pragma unroll
    for (int mt = 0; mt < 2; ++mt) {
        const int ch = p * 256 + wave * 32 + mt * 16 + quad * 4;
        const float4 bF = *(const float4*)(dil_b + ch);
        const float4 bG = *(const float4*)(dil_b + 512 + ch);
        #pragma unroll
        for (int n = 0; n < 8; ++n) {
            const int t = t0 + n * 16 + l15;
            float a0 = ftanh_(accF[mt][n][0] + bF.x) * fsigmoid(accG[mt][n][0] + bG.x);
            float a1 = ftanh_(accF[mt][n][1] + bF.y) * fsigmoid(accG[mt][n][1] + bG.y);
            float a2 = ftanh_(accF[mt][n][2] + bF.z) * fsigmoid(accG[mt][n][2] + bG.z);
            float a3 = ftanh_(accF[mt][n][3] + bF.w) * fsigmoid(accG[mt][n][3] + bG.w);
            v4u16 oh;
            oh[0] = bf16rne(a0); oh[1] = bf16rne(a1);
            oh[2] = bf16rne(a2); oh[3] = bf16rne(a3);
            *(v4u16*)(aHb + (size_t)t * RES_C + ch) = oh;
            if (split) {
                v4u16 ol;
                ol[0] = bf16rne(a0 - bf2f(oh[0]));
                ol[1] = bf16rne(a1 - bf2f(oh[1]));
                ol[2] = bf16rne(a2 - bf2f(oh[2]));
                ol[3] = bf16rne(a3 - bf2f(oh[3]));
                *(v4u16*)(aLb + (size_t)t * RES_C + ch) = ol;
            }
        }
    }
}

// ---------------- K3: x += res(a) (in place); skip += skipconv(a) ----------
// grid 512 = b(2) x 256 time-tiles of 32; 48 M-tiles over 8 waves.
// Weights consumed as a sequential per-wave fragment stream (Wq layout).
__global__ __launch_bounds__(512)
void k3_resskip(float* __restrict__ x,
                unsigned short* __restrict__ xH, unsigned short* __restrict__ xL,
                float* __restrict__ skip_acc,
                const unsigned short* __restrict__ aH,
                const unsigned short* __restrict__ aL,
                const unsigned short* __restrict__ Wq,   // this layer, frag-major
                const float* __restrict__ res_b, const float* __restrict__ skip_b,
                int split)
{
    __shared__ unsigned short shi[32 * 512];    // [t 32][c 512] bf16, swizzled
    __shared__ unsigned short slo[32 * 512];
    const int TC = split + 1;
    const int tid = threadIdx.x;
    const int wave = tid >> 6, lane = tid & 63;
    const int quad = lane >> 4, l15 = lane & 15;
    const int b = blockIdx.x >> 8;
    const int t0 = (blockIdx.x & 255) << 5;
    const unsigned short* wqw = Wq + (size_t)wave * 96 * TC * 512 + lane * 8;
    {
        // gload_lds staging: one full 1KB row per wave-call; content at chunk c
        // is global chunk c^(r&7) (matches reader's nsw XOR)
        #pragma unroll
        for (int q = 0; q < 4; ++q) {
            const int r = wave * 4 + q;
            const size_t go = (size_t)(b * TB + t0 + r) * RES_C + ((lane ^ (r & 7)) << 3);
            gld16(aH + go, shi + r * 512);
            if (split) gld16(aL + go, slo + r * 512);
        }
    }
    __syncthreads();
    const v4f vz = {0.f, 0.f, 0.f, 0.f};
    v4f acc[6][2];
    #pragma unroll
    for (int i = 0; i < 6; ++i) { acc[i][0] = vz; acc[i][1] = vz; }

    for (int kc = 0; kc < 16; ++kc) {
        const int nsw = ((kc * 4 + quad) ^ (l15 & 7)) << 3;
        v8s bh[2], bl[2];
        #pragma unroll
        for (int j = 0; j < 2; ++j) {
            bh[j] = *(const v8s*)(shi + (j * 16 + l15) * 512 + nsw);
            if (split) bl[j] = *(const v8s*)(slo + (j * 16 + l15) * 512 + nsw);
        }
        #pragma unroll
        for (int i = 0; i < 6; ++i) {
            const unsigned short* ck = wqw + (size_t)((kc * 6 + i) * TC) * 512;
            v8s ah, al;
            ah = *(const v8s*)(ck);
            if (split) al = *(const v8s*)(ck + 512);
            #pragma unroll
            for (int j = 0; j < 2; ++j) {
                acc[i][j] = __builtin_amdgcn_mfma_f32_16x16x32_bf16(ah, bh[j], acc[i][j], 0, 0, 0);
                if (split) {
                    acc[i][j] = __builtin_amdgcn_mfma_f32_16x16x32_bf16(ah, bl[j], acc[i][j], 0, 0, 0);
                    acc[i][j] = __builtin_amdgcn_mfma_f32_16x16x32_bf16(al, bh[j], acc[i][j], 0, 0, 0);
                }
            }
        }
    }
    #pragma unroll
    for (int i = 0; i < 6; ++i) {
        const int rb = (wave * 6 + i) * 16 + quad * 4;
        if (rb < 512) {
            const float4 bias = *(const float4*)(res_b + rb);
            #pragma unroll
            for (int j = 0; j < 2; ++j) {
                const int t = t0 + j * 16 + l15;
                const size_t o = (size_t)(b * TB + t) * RES_C + rb;
                float4 v = *(const float4*)(x + o);
                v.x += acc[i][j][0] + bias.x;
                v.y += acc[i][j][1] + bias.y;
                v.z += acc[i][j][2] + bias.z;
                v.w += acc[i][j][3] + bias.w;
                *(float4*)(x + o) = v;
                v4u16 oh;
                oh[0] = bf16rne(v.x); oh[1] = bf16rne(v.y);
                oh[2] = bf16rne(v.z); oh[3] = bf16rne(v.w);
                *(v4u16*)(xH + o) = oh;
                if (split) {
                    v4u16 ol;
                    ol[0] = bf16rne(v.x - bf2f(oh[0]));
                    ol[1] = bf16rne(v.y - bf2f(oh[1]));
                    ol[2] = bf16rne(v.z - bf2f(oh[2]));
                    ol[3] = bf16rne(v.w - bf2f(oh[3]));
                    *(v4u16*)(xL + o) = ol;
                }
            }
        } else {
            const int rs = rb - 512;
            const float4 bias = *(const float4*)(skip_b + rs);
            #pragma unroll
            for (int j = 0; j < 2; ++j) {
                const int t = t0 + j * 16 + l15;
                const size_t o = (size_t)(b * TB + t) * SKIP_C + rs;
                float4 v = *(const float4*)(skip_acc + o);
                v.x += acc[i][j][0] + bias.x;
                v.y += acc[i][j][1] + bias.y;
                v.z += acc[i][j][2] + bias.z;
                v.w += acc[i][j][3] + bias.w;
                *(float4*)(skip_acc + o) = v;
            }
        }
    }
}

// ---------------- final: out = tanh(fc2(relu(fc1(skip)))) ------------------
__global__ __launch_bounds__(256)
void k4_final(const float* __restrict__ skip_acc,
              const float* __restrict__ fc1_w, const float* __restrict__ fc1_b,
              const float* __restrict__ fc2_w, const float* __restrict__ fc2_b,
              float* __restrict__ out)
{
    __shared__ float stile[32 * 260];   // [t 32][c 256] fp32, row pad 4
    __shared__ float part[8][32];
    const int tid = threadIdx.x;
    const int b = blockIdx.x >> 8;
    const int t0 = (blockIdx.x & 255) << 5;
    {
        const int r = tid >> 3, sub = tid & 7;
        const float* srow = skip_acc + (size_t)(b * TB + t0 + r) * SKIP_C;
        float* drow = stile + r * 260;
        #pragma unroll
        for (int i = 0; i < 8; ++i) {
            const int c = (i * 8 + sub) * 4;
            *(float4*)(drow + c) = *(const float4*)(srow + c);
        }
    }
    __syncthreads();
    const int t = tid & 31;
    const int w = tid >> 5;             // 8 groups of 32 cout
    float y[32];
    #pragma unroll
    for (int co = 0; co < 32; ++co) y[co] = fc1_b[w * 32 + co];
    const float* srow = stile + t * 260;
    for (int ci = 0; ci < SKIP_C; ++ci) {
        const float s = srow[ci];
        const float* wcol = fc1_w + (size_t)(w * 32) * SKIP_C + ci;
        #pragma unroll
        for (int co = 0; co < 32; ++co)
            y[co] = fmaf(wcol[(size_t)co * SKIP_C], s, y[co]);
    }
    float partial = 0.f;
    #pragma unroll
    for (int co = 0; co < 32; ++co) {
        const float v = y[co] > 0.f ? y[co] : 0.f;
        partial = fmaf(fc2_w[w * 32 + co], v, partial);
    }
    part[w][t] = partial;
    __syncthreads();
    if (tid < 32) {
        float v = fc2_b[0];
        #pragma unroll
        for (int k = 0; k < 8; ++k) v += part[k][tid];
        out[(size_t)b * TB + t0 + tid] = ftanh_(v);
    }
}

// ---------------- host ----------------
extern "C" void kernel_launch(void* const* d_in, const int* in_sizes, int n_in,
                              void* d_out, int out_size, void* d_ws, size_t ws_size,
                              hipStream_t stream)
{
    const float* mel     = (const float*)d_in[0];
    const float* audio   = (const float*)d_in[1];
    const float* start_w = (const float*)d_in[2];
    const float* start_b = (const float*)d_in[3];
    const float* mel_w   = (const float*)d_in[4];
    const float* mel_b   = (const float*)d_in[5];
    const float* dil_b   = (const float*)d_in[7];
    const float* res_b   = (const float*)d_in[9];
    const float* skip_b  = (const float*)d_in[11];
    const float* fc1_w   = (const float*)d_in[12];
    const float* fc1_b   = (const float*)d_in[13];
    const float* fc2_w   = (const float*)d_in[14];
    const float* fc2_b   = (const float*)d_in[15];
    float* out = (float*)d_out;

    char* ws = (char*)d_ws;
    const size_t szX32 = (size_t)NBATCH * TB * RES_C * 4;      // 33.6 MB
    const size_t szX16 = (size_t)NBATCH * TB * RES_C * 2;      // 16.8 MB
    const size_t szSk = (size_t)NBATCH * TB * SKIP_C * 4;      // 16.8 MB
    // split decision: full (TC=2) footprint
    const size_t need2 = (size_t)NLAYERS * 3072 * 2 * 512 * 2  // Wp
                       + (size_t)NLAYERS * 768 * 2 * 512 * 2   // Wq
                       + szX32 + szSk + 4 * szX16;             // x, skip, xH/aH/xL/aL
    const int split = (ws_size >= need2) ? 1 : 0;
    const int TC = split + 1;
    const size_t szWp = (size_t)NLAYERS * 3072 * TC * 512 * 2;
    const size_t szWq = (size_t)NLAYERS * 768 * TC * 512 * 2;
    size_t off = 0;
    unsigned short* Wp = (unsigned short*)(ws + off); off += szWp;
    unsigned short* Wq = (unsigned short*)(ws + off); off += szWq;
    float* x = (float*)(ws + off); off += szX32;
    unsigned short* xH = (unsigned short*)(ws + off); off += szX16;
    unsigned short* aH = (unsigned short*)(ws + off); off += szX16;
    float* skip_acc = (float*)(ws + off); off += szSk;
    unsigned short* xL = split ? (unsigned short*)(ws + off) : xH; if (split) off += szX16;
    unsigned short* aL = split ? (unsigned short*)(ws + off) : aH; if (split) off += szX16;

    k0_pack<<<8192, 256, 0, stream>>>((const float*)d_in[6], (const float*)d_in[8],
                                      (const float*)d_in[10], Wp, Wq, split);
    k_init<<<NBATCH * (TB / 64), 512, 0, stream>>>(
        audio, mel, start_w, start_b, mel_w, mel_b, x, xH, xL, skip_acc, split);

    for (int l = 0; l < NLAYERS; ++l) {
        const int dil = 1 << (l % 10);
        k1_dilgate<<<256, 512, 0, stream>>>(xH, xL, aH, aL,
            Wp + (size_t)l * 3072 * TC * 512,
            dil_b + (size_t)l * 1024, dil, split);
        k3_resskip<<<512, 512, 0, stream>>>(x, xH, xL, skip_acc, aH, aL,
            Wq + (size_t)l * 768 * TC * 512,
            res_b + (size_t)l * 512, skip_b + (size_t)l * 256, split);
    }
    k4_final<<<512, 256, 0, stream>>>(skip_acc, fc1_w, fc1_b, fc2_w, fc2_b, out);
}

// Round 4
// 6945.609 us; speedup vs baseline: 1.5518x; 1.0443x over previous
//
#include <hip/hip_runtime.h>
#include <stdint.h>

#define TB 8192
#define NBATCH 2
#define RES_C 512
#define SKIP_C 256
#define MEL_C 80
#define NLAYERS 30

typedef short v8s __attribute__((ext_vector_type(8)));
typedef float v4f __attribute__((ext_vector_type(4)));
typedef unsigned short v4u16 __attribute__((ext_vector_type(4)));
typedef unsigned short v8u16 __attribute__((ext_vector_type(8)));

__device__ __forceinline__ unsigned short bf16rne(float f) {
    unsigned u = __float_as_uint(f);
    return (unsigned short)((u + 0x7fffu + ((u >> 16) & 1u)) >> 16);
}
__device__ __forceinline__ float bf2f(unsigned short h) {
    return __uint_as_float((unsigned)h << 16);
}
__device__ __forceinline__ float fsigmoid(float x) { return 1.0f / (1.0f + __expf(-x)); }
__device__ __forceinline__ float ftanh_(float x) { return 2.0f / (1.0f + __expf(-2.0f * x)) - 1.0f; }

// async 16B global->LDS (linear dest: wave-uniform base + lane*16)
__device__ __forceinline__ void gld16(const void* g, void* l) {
    __builtin_amdgcn_global_load_lds(
        (const __attribute__((address_space(1))) unsigned int*)g,
        (__attribute__((address_space(3))) unsigned int*)l, 16, 0, 0);
}

// ---------------- prep: pack weights fragment-major (dst-major, coalesced) --
// Wp layout (per layer): frag idx = (p*8+wv)*192 + ((tap*4+ks)*16 + kc*4 + mt*2 + fg),
// TC tiers per frag (H then L), frag body = [lane 64][8 bf16] = 1KB.
// Work-item = (l, co, ci-block of 8): reads 96B contiguous (8 cin x 3 taps),
// writes 6 x 16B; 64 consecutive work-items fill one frag's 64 lanes (coalesced).
// Wq layout (per layer): frag idx = wv*96 + kc*6 + i6 (rows (wv*6+i6)*16+l15,
// res rows 0..511 / skip rows 512..767), TC tiers, same 1KB frag body.
__global__ void k0_pack(const float* __restrict__ dil_w,
                        const float* __restrict__ res_w,
                        const float* __restrict__ skip_w,
                        unsigned short* __restrict__ Wp,
                        unsigned short* __restrict__ Wq,
                        int split)
{
    const int TC = split + 1;
    const int NWp = NLAYERS << 16;            // 1024 co x 64 ci-blocks per layer
    const int NWq = NLAYERS * 49152;          // 768 rows x 64 ci-blocks per layer
    const int total = NWp + NWq;
    const int stride = gridDim.x * blockDim.x;
    for (int i = blockIdx.x * blockDim.x + threadIdx.x; i < total; i += stride) {
        if (i < NWp) {
            // bits: l15(4) quad(2) kc(2) ks(2) mt(1) fg(1) wv(3) p(1) | l
            const int l15 = i & 15;
            const int quad = (i >> 4) & 3;
            const int kc = (i >> 6) & 3;
            const int ks = (i >> 8) & 3;
            const int mt = (i >> 10) & 1;
            const int fg = (i >> 11) & 1;
            const int wv = (i >> 12) & 7;
            const int p = (i >> 15) & 1;
            const int l = i >> 16;
            const int co = fg * 512 + p * 256 + wv * 32 + mt * 16 + l15;
            const int ci0 = ks * 128 + kc * 32 + quad * 8;
            const int lane = quad * 16 + l15;
            const float* src = dil_w + ((size_t)(l * 1024 + co) * 512 + ci0) * 3;
            float buf[24];
            #pragma unroll
            for (int q = 0; q < 6; ++q) {
                v4f v = *(const v4f*)(src + q * 4);
                buf[q * 4 + 0] = v[0]; buf[q * 4 + 1] = v[1];
                buf[q * 4 + 2] = v[2]; buf[q * 4 + 3] = v[3];
            }
            unsigned short* lbase = Wp + (size_t)l * 3072 * TC * 512 + lane * 8;
            #pragma unroll
            for (int tap = 0; tap < 3; ++tap) {
                v8u16 hi, lo;
                #pragma unroll
                for (int e = 0; e < 8; ++e) {
                    const float w = buf[e * 3 + tap];
                    const unsigned short h = bf16rne(w);
                    hi[e] = h;
                    lo[e] = bf16rne(w - bf2f(h));
                }
                const int idx = ((p * 8 + wv) * 192
                               + ((tap * 4 + ks) * 16 + kc * 4 + mt * 2 + fg)) * TC;
                unsigned short* d = lbase + (size_t)idx * 512;
                *(v8u16*)d = hi;
                if (split) *(v8u16*)(d + 512) = lo;
            }
        } else {
            const int j = i - NWp;
            const int l = j / 49152;
            const int r = j - l * 49152;
            // bits: l15(4) quad(2) kc(4) rowgrp(0..47)
            const int l15 = r & 15;
            const int quad = (r >> 4) & 3;
            const int kc = (r >> 6) & 15;
            const int rowgrp = r >> 10;
            const int rowc = rowgrp * 16 + l15;
            const int ci0 = kc * 32 + quad * 8;
            const int lane = quad * 16 + l15;
            const int wv = rowgrp / 6, i6 = rowgrp % 6;
            const float* src = (rowc < 512)
                ? res_w + ((size_t)(l * 512 + rowc) * 512 + ci0)
                : skip_w + ((size_t)(l * 256 + (rowc - 512)) * 512 + ci0);
            v4f v0 = *(const v4f*)(src);
            v4f v1 = *(const v4f*)(src + 4);
            float buf[8] = {v0[0], v0[1], v0[2], v0[3], v1[0], v1[1], v1[2], v1[3]};
            v8u16 hi, lo;
            #pragma unroll
            for (int e = 0; e < 8; ++e) {
                const float w = buf[e];
                const unsigned short h = bf16rne(w);
                hi[e] = h;
                lo[e] = bf16rne(w - bf2f(h));
            }
            const int idx = (wv * 96 + kc * 6 + i6) * TC;
            unsigned short* d = Wq + (size_t)l * 768 * TC * 512 + (size_t)idx * 512
                              + lane * 8;
            *(v8u16*)d = hi;
            if (split) *(v8u16*)(d + 512) = lo;
        }
    }
}

// ---------------- init: x0 = start_conv(audio) + mel_conv(mel) -------------
__global__ __launch_bounds__(512)
void k_init(const float* __restrict__ audio, const float* __restrict__ mel,
            const float* __restrict__ start_w, const float* __restrict__ start_b,
            const float* __restrict__ mel_w, const float* __restrict__ mel_b,
            float* __restrict__ x0,
            unsigned short* __restrict__ xH, unsigned short* __restrict__ xL,
            float* __restrict__ skip_acc, int split)
{
    __shared__ float smel[MEL_C][64];
    __shared__ float sa[64];
    const int tid = threadIdx.x;
    const int b = blockIdx.x >> 7;             // 128 tiles per batch
    const int t0 = (blockIdx.x & 127) << 6;
    for (int i = tid; i < MEL_C * 64; i += 512) {
        const int m = i >> 6, tt = i & 63;
        smel[m][tt] = mel[((size_t)b * MEL_C + m) * TB + t0 + tt];
    }
    if (tid < 64) sa[tid] = audio[(size_t)b * TB + t0 + tid];
    for (int i = tid; i < 64 * SKIP_C; i += 512) {
        const int tt = i >> 8, c = i & 255;
        skip_acc[(size_t)(b * TB + t0 + tt) * SKIP_C + c] = 0.f;
    }
    __syncthreads();
    const int c = tid;                          // 512 channels
    const float sw = start_w[c];
    const float bias = start_b[c] + mel_b[c];
    const float* wrow = mel_w + (size_t)c * MEL_C;
    v4f acc[16];
    #pragma unroll
    for (int q = 0; q < 16; ++q) {
        v4f av = *(const v4f*)&sa[q * 4];
        acc[q][0] = fmaf(sw, av[0], bias);
        acc[q][1] = fmaf(sw, av[1], bias);
        acc[q][2] = fmaf(sw, av[2], bias);
        acc[q][3] = fmaf(sw, av[3], bias);
    }
    for (int m = 0; m < MEL_C; ++m) {
        const float w = wrow[m];
        #pragma unroll
        for (int q = 0; q < 16; ++q) {
            v4f mv = *(const v4f*)&smel[m][q * 4];
            acc[q][0] = fmaf(w, mv[0], acc[q][0]);
            acc[q][1] = fmaf(w, mv[1], acc[q][1]);
            acc[q][2] = fmaf(w, mv[2], acc[q][2]);
            acc[q][3] = fmaf(w, mv[3], acc[q][3]);
        }
    }
    #pragma unroll
    for (int q = 0; q < 16; ++q) {
        #pragma unroll
        for (int e = 0; e < 4; ++e) {
            const int tt = q * 4 + e;
            const size_t o = (size_t)(b * TB + t0 + tt) * RES_C + c;
            const float v = acc[q][e];
            x0[o] = v;
            const unsigned short h = bf16rne(v);
            xH[o] = h;
            if (split) xL[o] = bf16rne(v - bf2f(h));
        }
    }
}

// ---------------- K1: a = tanh(f)*sigmoid(g), f,g = dilated conv -----------
// grid 256 = 128 time-tiles(128 wide) x 2 channel-chunks(p); p aligns with XCD
// parity (idx&1) so each XCD's L2 holds one 3.15MB weight half.
// Weights consumed as a sequential per-wave fragment stream (Wp layout).
__global__ __launch_bounds__(512)
void k1_dilgate(const unsigned short* __restrict__ xH,
                const unsigned short* __restrict__ xL,
                unsigned short* __restrict__ aH, unsigned short* __restrict__ aL,
                const unsigned short* __restrict__ Wp,   // this layer, frag-major
                const float* __restrict__ dil_b,         // [1024] this layer
                int dil, int split)
{
    __shared__ unsigned short shb2[2][128 * 128];   // [buf][t 128][k 128] bf16 hi, swizzled
    __shared__ unsigned short slb2[2][128 * 128];   // lo
    const int TC = split + 1;
    const int tid = threadIdx.x;
    const int wave = tid >> 6, lane = tid & 63;
    const int quad = lane >> 4, l15 = lane & 15;
    const int p = blockIdx.x & 1;
    const int tl = blockIdx.x >> 1;
    const int b = tl >> 6;
    const int t0 = (tl & 63) << 7;
    const int srow = lane >> 4;          // 0..3 within a 4-row staging call
    const int schunk = lane & 15;        // 16B chunk within row
    // per-wave weight stream base (frag stride 512 shorts = 1KB)
    const unsigned short* wpw = Wp + ((size_t)(p * 8 + wave) * 192 * TC) * 512 + lane * 8;

    const v4f vz = {0.f, 0.f, 0.f, 0.f};
    v4f accF[2][8], accG[2][8];
    #pragma unroll
    for (int mt = 0; mt < 2; ++mt)
        #pragma unroll
        for (int n = 0; n < 8; ++n) { accF[mt][n] = vz; accG[mt][n] = vz; }

    auto stage = [&](int chunk, int buf) {
        const int tap = chunk >> 2, ks = chunk & 3;
        const int off = (tap - 1) * dil;
        const bool allok = (t0 + off >= 0) && (t0 + 127 + off < TB);  // block-uniform
        unsigned short* dsth = shb2[buf];
        unsigned short* dstl = slb2[buf];
        if (allok) {
            #pragma unroll
            for (int q = 0; q < 4; ++q) {
                const int rbase = wave * 16 + q * 4;
                const int r = rbase + srow;
                const size_t go = (size_t)(b * TB + t0 + r + off) * RES_C
                                + ks * 128 + ((schunk ^ (r & 7)) << 3);
                gld16(xH + go, dsth + rbase * 128);
                if (split) gld16(xL + go, dstl + rbase * 128);
            }
        } else {
            #pragma unroll
            for (int q = 0; q < 4; ++q) {
                const int rbase = wave * 16 + q * 4;
                const int r = rbase + srow;
                const int tsrc = t0 + r + off;
                const bool ok = (unsigned)tsrc < TB;
                const size_t go = (size_t)(b * TB + tsrc) * RES_C
                                + ks * 128 + ((schunk ^ (r & 7)) << 3);
                v8u16 vh = ok ? *(const v8u16*)(xH + go) : (v8u16)0;
                *(v8u16*)(dsth + rbase * 128 + (lane << 3)) = vh;
                if (split) {
                    v8u16 vl = ok ? *(const v8u16*)(xL + go) : (v8u16)0;
                    *(v8u16*)(dstl + rbase * 128 + (lane << 3)) = vl;
                }
            }
        }
    };

    auto compute = [&](int chunk, int buf) {
        const int tap = chunk >> 2, ks = chunk & 3;
        const unsigned short* cb = wpw + (size_t)((tap * 4 + ks) * 16) * TC * 512;
        const unsigned short* shb = shb2[buf];
        const unsigned short* slb = slb2[buf];
        #pragma unroll
        for (int kc = 0; kc < 4; ++kc) {
            const unsigned short* ck = cb + (size_t)(kc * 4) * TC * 512;
            v8s afh[2], agh[2], afl[2], agl[2];
            #pragma unroll
            for (int mt = 0; mt < 2; ++mt) {
                afh[mt] = *(const v8s*)(ck + (size_t)((mt * 2 + 0) * TC) * 512);
                agh[mt] = *(const v8s*)(ck + (size_t)((mt * 2 + 1) * TC) * 512);
                if (split) {
                    afl[mt] = *(const v8s*)(ck + (size_t)((mt * 2 + 0) * TC + 1) * 512);
                    agl[mt] = *(const v8s*)(ck + (size_t)((mt * 2 + 1) * TC + 1) * 512);
                }
            }
            const int nsw = ((kc * 4 + quad) ^ (l15 & 7)) << 3;
            #pragma unroll
            for (int nh = 0; nh < 2; ++nh) {
                v8s bh[4], bl[4];
                #pragma unroll
                for (int j = 0; j < 4; ++j) {
                    const int trow = (nh * 4 + j) * 16 + l15;
                    bh[j] = *(const v8s*)(shb + trow * 128 + nsw);
                    if (split) bl[j] = *(const v8s*)(slb + trow * 128 + nsw);
                }
                #pragma unroll
                for (int mt = 0; mt < 2; ++mt)
                    #pragma unroll
                    for (int j = 0; j < 4; ++j) {
                        const int n = nh * 4 + j;
                        accF[mt][n] = __builtin_amdgcn_mfma_f32_16x16x32_bf16(
                            afh[mt], bh[j], accF[mt][n], 0, 0, 0);
                        accG[mt][n] = __builtin_amdgcn_mfma_f32_16x16x32_bf16(
                            agh[mt], bh[j], accG[mt][n], 0, 0, 0);
                        if (split) {
                            accF[mt][n] = __builtin_amdgcn_mfma_f32_16x16x32_bf16(
                                afh[mt], bl[j], accF[mt][n], 0, 0, 0);
                            accF[mt][n] = __builtin_amdgcn_mfma_f32_16x16x32_bf16(
                                afl[mt], bh[j], accF[mt][n], 0, 0, 0);
                            accG[mt][n] = __builtin_amdgcn_mfma_f32_16x16x32_bf16(
                                agh[mt], bl[j], accG[mt][n], 0, 0, 0);
                            accG[mt][n] = __builtin_amdgcn_mfma_f32_16x16x32_bf16(
                                agl[mt], bh[j], accG[mt][n], 0, 0, 0);
                        }
                    }
            }
        }
    };

    stage(0, 0);
    __syncthreads();                       // drain prologue stage
    for (int chunk = 0; chunk < 12; ++chunk) {
        if (chunk < 11) stage(chunk + 1, (chunk + 1) & 1);  // async, other buffer
        compute(chunk, chunk & 1);
        __syncthreads();                   // vmcnt(0)+lgkmcnt(0)+barrier: next buf ready
    }

    // gate epilogue: f,g tiles share C-layout -> in-register gating
    unsigned short* aHb = aH + (size_t)b * TB * RES_C;
    unsigned short* aLb = aL + (size_t)b * TB * RES_C;
    #pragma unroll
    for (int mt = 0; mt < 2; ++mt) {
        const int ch = p * 256 + wave * 32 + mt * 16 + quad * 4;
        const float4 bF = *(const float4*)(dil_b + ch);
        const float4 bG = *(const float4*)(dil_b + 512 + ch);
        #pragma unroll
        for (int n = 0; n < 8; ++n) {
            const int t = t0 + n * 16 + l15;
            float a0 = ftanh_(accF[mt][n][0] + bF.x) * fsigmoid(accG[mt][n][0] + bG.x);
            float a1 = ftanh_(accF[mt][n][1] + bF.y) * fsigmoid(accG[mt][n][1] + bG.y);
            float a2 = ftanh_(accF[mt][n][2] + bF.z) * fsigmoid(accG[mt][n][2] + bG.z);
            float a3 = ftanh_(accF[mt][n][3] + bF.w) * fsigmoid(accG[mt][n][3] + bG.w);
            v4u16 oh;
            oh[0] = bf16rne(a0); oh[1] = bf16rne(a1);
            oh[2] = bf16rne(a2); oh[3] = bf16rne(a3);
            *(v4u16*)(aHb + (size_t)t * RES_C + ch) = oh;
            if (split) {
                v4u16 ol;
                ol[0] = bf16rne(a0 - bf2f(oh[0]));
                ol[1] = bf16rne(a1 - bf2f(oh[1]));
                ol[2] = bf16rne(a2 - bf2f(oh[2]));
                ol[3] = bf16rne(a3 - bf2f(oh[3]));
                *(v4u16*)(aLb + (size_t)t * RES_C + ch) = ol;
            }
        }
    }
}

// ---------------- K3: x += res(a) (in place); skip += skipconv(a) ----------
// grid 512 = b(2) x 256 time-tiles of 32; 48 M-tiles over 8 waves.
// Weights consumed as a sequential per-wave fragment stream (Wq layout).
__global__ __launch_bounds__(512)
void k3_resskip(float* __restrict__ x,
                unsigned short* __restrict__ xH, unsigned short* __restrict__ xL,
                float* __restrict__ skip_acc,
                const unsigned short* __restrict__ aH,
                const unsigned short* __restrict__ aL,
                const unsigned short* __restrict__ Wq,   // this layer, frag-major
                const float* __restrict__ res_b, const float* __restrict__ skip_b,
                int split)
{
    __shared__ unsigned short shi[32 * 512];    // [t 32][c 512] bf16, swizzled
    __shared__ unsigned short slo[32 * 512];
    const int TC = split + 1;
    const int tid = threadIdx.x;
    const int wave = tid >> 6, lane = tid & 63;
    const int quad = lane >> 4, l15 = lane & 15;
    const int b = blockIdx.x >> 8;
    const int t0 = (blockIdx.x & 255) << 5;
    const unsigned short* wqw = Wq + (size_t)wave * 96 * TC * 512 + lane * 8;
    {
        // gload_lds staging: one full 1KB row per wave-call; content at chunk c
        // is global chunk c^(r&7) (matches reader's nsw XOR)
        #pragma unroll
        for (int q = 0; q < 4; ++q) {
            const int r = wave * 4 + q;
            const size_t go = (size_t)(b * TB + t0 + r) * RES_C + ((lane ^ (r & 7)) << 3);
            gld16(aH + go, shi + r * 512);
            if (split) gld16(aL + go, slo + r * 512);
        }
    }
    __syncthreads();
    const v4f vz = {0.f, 0.f, 0.f, 0.f};
    v4f acc[6][2];
    #pragma unroll
    for (int i = 0; i < 6; ++i) { acc[i][0] = vz; acc[i][1] = vz; }

    for (int kc = 0; kc < 16; ++kc) {
        const int nsw = ((kc * 4 + quad) ^ (l15 & 7)) << 3;
        v8s bh[2], bl[2];
        #pragma unroll
        for (int j = 0; j < 2; ++j) {
            bh[j] = *(const v8s*)(shi + (j * 16 + l15) * 512 + nsw);
            if (split) bl[j] = *(const v8s*)(slo + (j * 16 + l15) * 512 + nsw);
        }
        #pragma unroll
        for (int i = 0; i < 6; ++i) {
            const unsigned short* ck = wqw + (size_t)((kc * 6 + i) * TC) * 512;
            v8s ah, al;
            ah = *(const v8s*)(ck);
            if (split) al = *(const v8s*)(ck + 512);
            #pragma unroll
            for (int j = 0; j < 2; ++j) {
                acc[i][j] = __builtin_amdgcn_mfma_f32_16x16x32_bf16(ah, bh[j], acc[i][j], 0, 0, 0);
                if (split) {
                    acc[i][j] = __builtin_amdgcn_mfma_f32_16x16x32_bf16(ah, bl[j], acc[i][j], 0, 0, 0);
                    acc[i][j] = __builtin_amdgcn_mfma_f32_16x16x32_bf16(al, bh[j], acc[i][j], 0, 0, 0);
                }
            }
        }
    }
    #pragma unroll
    for (int i = 0; i < 6; ++i) {
        const int rb = (wave * 6 + i) * 16 + quad * 4;
        if (rb < 512) {
            const float4 bias = *(const float4*)(res_b + rb);
            #pragma unroll
            for (int j = 0; j < 2; ++j) {
                const int t = t0 + j * 16 + l15;
                const size_t o = (size_t)(b * TB + t) * RES_C + rb;
                float4 v = *(const float4*)(x + o);
                v.x += acc[i][j][0] + bias.x;
                v.y += acc[i][j][1] + bias.y;
                v.z += acc[i][j][2] + bias.z;
                v.w += acc[i][j][3] + bias.w;
                *(float4*)(x + o) = v;
                v4u16 oh;
                oh[0] = bf16rne(v.x); oh[1] = bf16rne(v.y);
                oh[2] = bf16rne(v.z); oh[3] = bf16rne(v.w);
                *(v4u16*)(xH + o) = oh;
                if (split) {
                    v4u16 ol;
                    ol[0] = bf16rne(v.x - bf2f(oh[0]));
                    ol[1] = bf16rne(v.y - bf2f(oh[1]));
                    ol[2] = bf16rne(v.z - bf2f(oh[2]));
                    ol[3] = bf16rne(v.w - bf2f(oh[3]));
                    *(v4u16*)(xL + o) = ol;
                }
            }
        } else {
            const int rs = rb - 512;
            const float4 bias = *(const float4*)(skip_b + rs);
            #pragma unroll
            for (int j = 0; j < 2; ++j) {
                const int t = t0 + j * 16 + l15;
                const size_t o = (size_t)(b * TB + t) * SKIP_C + rs;
                float4 v = *(const float4*)(skip_acc + o);
                v.x += acc[i][j][0] + bias.x;
                v.y += acc[i][j][1] + bias.y;
                v.z += acc[i][j][2] + bias.z;
                v.w += acc[i][j][3] + bias.w;
                *(float4*)(skip_acc + o) = v;
            }
        }
    }
}

// ---------------- final: out = tanh(fc2(relu(fc1(skip)))) ------------------
__global__ __launch_bounds__(256)
void k4_final(const float* __restrict__ skip_acc,
              const float* __restrict__ fc1_w, const float* __restrict__ fc1_b,
              const float* __restrict__ fc2_w, const float* __restrict__ fc2_b,
              float* __restrict__ out)
{
    __shared__ float stile[32 * 260];   // [t 32][c 256] fp32, row pad 4
    __shared__ float part[8][32];
    const int tid = threadIdx.x;
    const int b = blockIdx.x >> 8;
    const int t0 = (blockIdx.x & 255) << 5;
    {
        const int r = tid >> 3, sub = tid & 7;
        const float* srow = skip_acc + (size_t)(b * TB + t0 + r) * SKIP_C;
        float* drow = stile + r * 260;
        #pragma unroll
        for (int i = 0; i < 8; ++i) {
            const int c = (i * 8 + sub) * 4;
            *(float4*)(drow + c) = *(const float4*)(srow + c);
        }
    }
    __syncthreads();
    const int t = tid & 31;
    const int w = tid >> 5;             // 8 groups of 32 cout
    float y[32];
    #pragma unroll
    for (int co = 0; co < 32; ++co) y[co] = fc1_b[w * 32 + co];
    const float* srow = stile + t * 260;
    for (int ci = 0; ci < SKIP_C; ++ci) {
        const float s = srow[ci];
        const float* wcol = fc1_w + (size_t)(w * 32) * SKIP_C + ci;
        #pragma unroll
        for (int co = 0; co < 32; ++co)
            y[co] = fmaf(wcol[(size_t)co * SKIP_C], s, y[co]);
    }
    float partial = 0.f;
    #pragma unroll
    for (int co = 0; co < 32; ++co) {
        const float v = y[co] > 0.f ? y[co] : 0.f;
        partial = fmaf(fc2_w[w * 32 + co], v, partial);
    }
    part[w][t] = partial;
    __syncthreads();
    if (tid < 32) {
        float v = fc2_b[0];
        #pragma unroll
        for (int k = 0; k < 8; ++k) v += part[k][tid];
        out[(size_t)b * TB + t0 + tid] = ftanh_(v);
    }
}

// ---------------- host ----------------
extern "C" void kernel_launch(void* const* d_in, const int* in_sizes, int n_in,
                              void* d_out, int out_size, void* d_ws, size_t ws_size,
                              hipStream_t stream)
{
    const float* mel     = (const float*)d_in[0];
    const float* audio   = (const float*)d_in[1];
    const float* start_w = (const float*)d_in[2];
    const float* start_b = (const float*)d_in[3];
    const float* mel_w   = (const float*)d_in[4];
    const float* mel_b   = (const float*)d_in[5];
    const float* dil_b   = (const float*)d_in[7];
    const float* res_b   = (const float*)d_in[9];
    const float* skip_b  = (const float*)d_in[11];
    const float* fc1_w   = (const float*)d_in[12];
    const float* fc1_b   = (const float*)d_in[13];
    const float* fc2_w   = (const float*)d_in[14];
    const float* fc2_b   = (const float*)d_in[15];
    float* out = (float*)d_out;

    char* ws = (char*)d_ws;
    const size_t szX32 = (size_t)NBATCH * TB * RES_C * 4;      // 33.6 MB
    const size_t szX16 = (size_t)NBATCH * TB * RES_C * 2;      // 16.8 MB
    const size_t szSk = (size_t)NBATCH * TB * SKIP_C * 4;      // 16.8 MB
    // split decision: full (TC=2) footprint
    const size_t need2 = (size_t)NLAYERS * 3072 * 2 * 512 * 2  // Wp
                       + (size_t)NLAYERS * 768 * 2 * 512 * 2   // Wq
                       + szX32 + szSk + 4 * szX16;             // x, skip, xH/aH/xL/aL
    const int split = (ws_size >= need2) ? 1 : 0;
    const int TC = split + 1;
    const size_t szWp = (size_t)NLAYERS * 3072 * TC * 512 * 2;
    const size_t szWq = (size_t)NLAYERS * 768 * TC * 512 * 2;
    size_t off = 0;
    unsigned short* Wp = (unsigned short*)(ws + off); off += szWp;
    unsigned short* Wq = (unsigned short*)(ws + off); off += szWq;
    float* x = (float*)(ws + off); off += szX32;
    unsigned short* xH = (unsigned short*)(ws + off); off += szX16;
    unsigned short* aH = (unsigned short*)(ws + off); off += szX16;
    float* skip_acc = (float*)(ws + off); off += szSk;
    unsigned short* xL = split ? (unsigned short*)(ws + off) : xH; if (split) off += szX16;
    unsigned short* aL = split ? (unsigned short*)(ws + off) : aH; if (split) off += szX16;

    k0_pack<<<8192, 256, 0, stream>>>((const float*)d_in[6], (const float*)d_in[8],
                                      (const float*)d_in[10], Wp, Wq, split);
    k_init<<<NBATCH * (TB / 64), 512, 0, stream>>>(
        audio, mel, start_w, start_b, mel_w, mel_b, x, xH, xL, skip_acc, split);

    for (int l = 0; l < NLAYERS; ++l) {
        const int dil = 1 << (l % 10);
        k1_dilgate<<<256, 512, 0, stream>>>(xH, xL, aH, aL,
            Wp + (size_t)l * 3072 * TC * 512,
            dil_b + (size_t)l * 1024, dil, split);
        k3_resskip<<<512, 512, 0, stream>>>(x, xH, xL, skip_acc, aH, aL,
            Wq + (size_t)l * 768 * TC * 512,
            res_b + (size_t)l * 512, skip_b + (size_t)l * 256, split);
    }
    k4_final<<<512, 256, 0, stream>>>(skip_acc, fc1_w, fc1_b, fc2_w, fc2_b, out);
}